// Round 16
// baseline (377.597 us; speedup 1.0000x reference)
//
#include <hip/hip_runtime.h>

// EMA Vector-Quantizer for MI355X (gfx950).
// N=16384 tokens, D=64, K=8192. Dominant cost: 16384x8192x64 fp32 GEMM for
// distance argmin (no fp32 MFMA on CDNA4 -> VALU; v_pk_fma_f32 floor 54.6us).
// Established (R13-R15): binding resource is vector-memory operand return;
// w on the SCALAR path (wave-uniform s_load -> SGPR operand of v_pk_fma_f32)
// + z in LDS cut k_argmin 293 -> 219us. Residual: s_load/ds_read lgkmcnt
// mixing forces per-iter drains, and 64KB z_s capped cover at 4 waves/SIMD
// (true VALU busy ~35%).
// R16 re-tile: TN=128 (z_s 32KB -> 4 blocks/CU -> 8 waves/SIMD, double the
// latency cover) and 2 tokens x 16 codes per lane-chunk (acc2[2][8] = 32
// VGPRs, demand ~55 < 64). Per d-iter: 1 ds_read_b64 + 64B s_load + 16
// pk_fma -> FMA issue is the top pipe (54.6us), LDS ~20us, scalar path free.

#define N_TOK 16384
#define K_EMB 8192
#define EMB_D 64
#define TN 128
#define GROUPS 8
#define KPG (K_EMB / GROUPS)   // 1024 codes per k-group; 128 per wave

typedef float v2f __attribute__((ext_vector_type(2)));

// d_out flat layout (float32), in reference return order:
// z_q (1048576) | loss | new_weight (524288) | new_cluster_size (8192) | new_embed_avg (524288)
#define OFF_LOSS 1048576
#define OFF_W    1048577
#define OFF_CS   1572865
#define OFF_EA   1581057

// scratch inside the z_q region of out (all < 1048576, overwritten by k_quant)
#define OUT_WT 0                        // w_t[d][k]: 64 x 8192 = 524288 floats
#define OUT_CD 524288                   // cand dist [GROUPS][N_TOK] = 131072
#define OUT_CI (524288 + 131072)        // cand idx  [GROUPS][N_TOK] = 131072

// ws float offsets
#define WS_NSUM  0
#define WS_LOSS  1
#define WS_WNORM 16
#define WS_IDX   (WS_WNORM + K_EMB)

// ---------------------------------------------------------------------------
// K0: wnorm[k]; transpose weight -> w_t[d][k] (in out); zero accumulators.
__global__ void k_prep(const float* __restrict__ weight,
                       float* __restrict__ out, float* __restrict__ ws) {
  int gid = blockIdx.x * 256 + threadIdx.x;     // 0..131071
  int row = gid >> 4;                            // codebook row 0..8191
  int l16 = gid & 15;
  float4 w4 = *(const float4*)(weight + row * EMB_D + l16 * 4);
  float s = w4.x * w4.x + w4.y * w4.y + w4.z * w4.z + w4.w * w4.w;
  #pragma unroll
  for (int off = 8; off > 0; off >>= 1) s += __shfl_xor(s, off, 16);
  if (l16 == 0) ws[WS_WNORM + row] = s;

  // transposed copy: w_t[d*8192 + row], d = l16*4+c
  out[OUT_WT + (l16 * 4 + 0) * K_EMB + row] = w4.x;
  out[OUT_WT + (l16 * 4 + 1) * K_EMB + row] = w4.y;
  out[OUT_WT + (l16 * 4 + 2) * K_EMB + row] = w4.z;
  out[OUT_WT + (l16 * 4 + 3) * K_EMB + row] = w4.w;

  #pragma unroll
  for (int j = 0; j < 4; ++j) out[OFF_EA + gid * 4 + j] = 0.f;
  if (gid < K_EMB) out[OFF_CS + gid] = 0.f;
  if (gid == 0) { out[OFF_LOSS] = 0.f; ws[WS_NSUM] = 0.f; ws[WS_LOSS] = 0.f; }
}

// ---------------------------------------------------------------------------
// K1: distance argmin. Block = 512 threads = 8 waves sharing 128 tokens;
// wave w scans k-range [kbase + w*128, +128) in 8 chunks of 16 codes;
// lane owns 2 tokens. grid (128, 8) = 1024 blocks = 4/CU -> 8 waves/SIMD.
// Per d-iter: 1 ds_read_b64 (z pair) + wave-uniform 64B s_load (w, SGPRs)
// + 16 v_pk_fma_f32 (acc2[2][8] = 32 VGPRs; SGPR pair is the one scalar
// operand each pk_fma is allowed).
__global__ __launch_bounds__(512) void k_argmin(
    const float* __restrict__ z, const float* __restrict__ wt,
    const float* __restrict__ wnorm, float* __restrict__ cd,
    int* __restrict__ ci) {
  __shared__ __align__(16) float z_s[EMB_D * TN];  // [d][n], 32 KB
  const int t = threadIdx.x;
  const int n0 = blockIdx.x * TN;
  const int kbase = blockIdx.y * KPG;
  // z is (b, c, hw): z_flat[n][d] = z[b*65536 + d*1024 + hw], n = b*1024+hw.
  // TN=128 stays within one 1024-aligned b-slab (n0 is a multiple of 128).
  const float* zb = z + ((n0 >> 10) << 16) + (n0 & 1023);

  // 8192 floats = 2048 float4s; 512 threads -> 4 iterations.
  #pragma unroll
  for (int i = 0; i < 4; ++i) {
    int f4 = i * 512 + t;                 // 0..2047 float4s
    int d = f4 >> 5, c4 = (f4 & 31) * 4;
    *(float4*)(z_s + d * TN + c4) = *(const float4*)(zb + d * 1024 + c4);
  }
  __syncthreads();

  const int lane = t & 63;
  // wave id: provably wave-uniform -> w addresses become SGPR (s_load).
  const int wid = __builtin_amdgcn_readfirstlane(t >> 6);
  const int k0base = kbase + wid * 128;
  const float* zlane = z_s + lane * 2;    // this lane's 2 tokens

  float bestd[2];
  int besti[2];
  #pragma unroll
  for (int i = 0; i < 2; ++i) { bestd[i] = 3.4e38f; besti[i] = 0; }

  for (int kc = 0; kc < 8; ++kc) {        // 8 chunks of 16 codes
    const int k0 = k0base + kc * 16;
    const float* wrow = wt + k0;          // + d*K_EMB per d; uniform address

    v2f acc2[2][8];                       // [n][k-pair]; .x=k even, .y=k odd
    #pragma unroll
    for (int n = 0; n < 2; ++n)
      #pragma unroll
      for (int p = 0; p < 8; ++p) acc2[n][p] = (v2f)(0.f);

    #pragma unroll 4
    for (int d = 0; d < EMB_D; ++d) {
      v2f zf = *(const v2f*)(zlane + d * TN);         // ds_read_b64
      const v2f* wv = (const v2f*)(wrow + (size_t)d * K_EMB);  // s_load 64B
      v2f z0 = {zf.x, zf.x};
      v2f z1 = {zf.y, zf.y};
      #pragma unroll
      for (int p = 0; p < 8; ++p) {
        v2f w2 = wv[p];
        acc2[0][p] = __builtin_elementwise_fma(z0, w2, acc2[0][p]);
        acc2[1][p] = __builtin_elementwise_fma(z1, w2, acc2[1][p]);
      }
    }

    // dist = |w|^2 - 2*dot; k ascends (kc, kk) + strict <  == first-min.
    #pragma unroll
    for (int kk = 0; kk < 16; ++kk) {
      float wn = wnorm[k0 + kk];          // uniform -> scalar load
      #pragma unroll
      for (int n = 0; n < 2; ++n) {
        float dot = (kk & 1) ? acc2[n][kk >> 1].y : acc2[n][kk >> 1].x;
        float dist = fmaf(-2.f, dot, wn);
        if (dist < bestd[n]) { bestd[n] = dist; besti[n] = k0 + kk; }
      }
    }
  }

  // Block combine: stash per-wave bests in z_s (done reading it), then the
  // first 128 threads reduce 8 waves in ascending-k order (waves cover
  // ascending k-ranges, so strict < keeps the smaller k on ties).
  __syncthreads();
  #pragma unroll
  for (int i = 0; i < 2; ++i) {
    int n = lane * 2 + i;
    z_s[wid * TN + n] = bestd[i];
    ((int*)z_s)[1024 + wid * TN + n] = besti[i];
  }
  __syncthreads();
  if (t < TN) {
    int n = t;
    float bd = z_s[n];
    int bi = ((int*)z_s)[1024 + n];
    #pragma unroll
    for (int w = 1; w < 8; ++w) {
      float od = z_s[w * TN + n];
      int oi = ((int*)z_s)[1024 + w * TN + n];
      if (od < bd) { bd = od; bi = oi; }
    }
    cd[blockIdx.y * N_TOK + n0 + n] = bd;
    ci[blockIdx.y * N_TOK + n0 + n] = bi;
  }
}

// ---------------------------------------------------------------------------
// K2: reduce the GROUPS candidates per token; enc_sum atomics.
// Groups cover ascending k-ranges, so strict < keeps smallest index on tie.
__global__ void k_reduce(const float* __restrict__ cd, const int* __restrict__ ci,
                         int* __restrict__ idx, float* __restrict__ enc) {
  int n = blockIdx.x * 256 + threadIdx.x;
  float bd = cd[n]; int bi = ci[n];
  #pragma unroll
  for (int g = 1; g < GROUPS; ++g) {
    float od = cd[g * N_TOK + n];
    int oi = ci[g * N_TOK + n];
    if (od < bd) { bd = od; bi = oi; }
  }
  idx[n] = bi;
  atomicAdd(enc + bi, 1.0f);
}

// ---------------------------------------------------------------------------
// K3: z_q gather + straight-through output + loss partials + embed_sum atomics.
__global__ void k_quant(const float* __restrict__ z, const float* __restrict__ weight,
                        const int* __restrict__ idx, float* __restrict__ out,
                        float* __restrict__ embed_acc, float* __restrict__ ws) {
  int base = blockIdx.x * 1024 + threadIdx.x;
  float lsum = 0.f;
  #pragma unroll
  for (int i = 0; i < 4; ++i) {
    int e = base + i * 256;               // (b,c,hw) flat, same layout as z
    int c = (e >> 10) & 63;
    int n = ((e >> 16) << 10) | (e & 1023);
    int k = idx[n];
    float zv = z[e];
    float q = weight[k * EMB_D + c];
    out[e] = zv + (q - zv);               // straight-through value
    float d = q - zv;
    lsum += d * d;
    atomicAdd(embed_acc + k * EMB_D + c, zv);
  }
  #pragma unroll
  for (int off = 32; off > 0; off >>= 1) lsum += __shfl_xor(lsum, off, 64);
  __shared__ float red[4];
  int lane = threadIdx.x & 63, wv = threadIdx.x >> 6;
  if (lane == 0) red[wv] = lsum;
  __syncthreads();
  if (threadIdx.x == 0)
    atomicAdd(ws + WS_LOSS, red[0] + red[1] + red[2] + red[3]);
}

// ---------------------------------------------------------------------------
// K4: new_cluster_size (in place over enc_sum), n-sum, loss finalize.
__global__ void k_cluster(const float* __restrict__ cluster_in,
                          float* __restrict__ out, float* __restrict__ ws) {
  int k = blockIdx.x * 256 + threadIdx.x;
  float ncs = cluster_in[k] * 0.99f + 0.01f * out[OFF_CS + k];
  out[OFF_CS + k] = ncs;
  float s = ncs;
  #pragma unroll
  for (int off = 32; off > 0; off >>= 1) s += __shfl_xor(s, off, 64);
  __shared__ float red[4];
  int lane = threadIdx.x & 63, wv = threadIdx.x >> 6;
  if (lane == 0) red[wv] = s;
  __syncthreads();
  if (threadIdx.x == 0) atomicAdd(ws + WS_NSUM, red[0] + red[1] + red[2] + red[3]);
  if (blockIdx.x == 0 && threadIdx.x == 0)
    out[OFF_LOSS] = 0.25f * ws[WS_LOSS] * (1.0f / 1048576.0f);
}

// ---------------------------------------------------------------------------
// K5: smoothed cluster sizes -> new_weight; new_embed_avg (in place).
__global__ void k_final(const float* __restrict__ embed_avg,
                        float* __restrict__ out, const float* __restrict__ ws) {
  int e = blockIdx.x * 256 + threadIdx.x;   // < 524288
  int k = e >> 6;
  float ncs = out[OFF_CS + k];
  float nsum = ws[WS_NSUM];
  float sm = (ncs + 1e-5f) / (nsum + K_EMB * 1e-5f) * nsum;
  float ea = embed_avg[e] * 0.99f + 0.01f * out[OFF_EA + e];
  out[OFF_EA + e] = ea;
  out[OFF_W + e] = ea / sm;
}

// ---------------------------------------------------------------------------
extern "C" void kernel_launch(void* const* d_in, const int* in_sizes, int n_in,
                              void* d_out, int out_size, void* d_ws, size_t ws_size,
                              hipStream_t stream) {
  const float* z = (const float*)d_in[0];
  const float* weight = (const float*)d_in[1];
  const float* cluster = (const float*)d_in[2];
  const float* embed_avg = (const float*)d_in[3];
  float* out = (float*)d_out;
  float* ws = (float*)d_ws;
  float* wnorm = ws + WS_WNORM;
  int* idx = (int*)(ws + WS_IDX);
  float* wt = out + OUT_WT;               // scratch in z_q region
  float* cd = out + OUT_CD;
  int* ci = (int*)(out + OUT_CI);

  hipLaunchKernelGGL(k_prep, dim3(512), dim3(256), 0, stream, weight, out, ws);
  hipLaunchKernelGGL(k_argmin, dim3(N_TOK / TN, GROUPS), dim3(512), 0, stream,
                     z, wt, wnorm, cd, ci);
  hipLaunchKernelGGL(k_reduce, dim3(N_TOK / 256), dim3(256), 0, stream,
                     cd, ci, idx, out + OFF_CS);
  hipLaunchKernelGGL(k_quant, dim3(1024), dim3(256), 0, stream,
                     z, weight, idx, out, out + OFF_EA, ws);
  hipLaunchKernelGGL(k_cluster, dim3(K_EMB / 256), dim3(256), 0, stream,
                     cluster, out, ws);
  hipLaunchKernelGGL(k_final, dim3(524288 / 256), dim3(256), 0, stream,
                     embed_avg, out, ws);
}

// Round 17
// 367.124 us; speedup vs baseline: 1.0285x; 1.0285x over previous
//
#include <hip/hip_runtime.h>

// EMA Vector-Quantizer for MI355X (gfx950).
// N=16384 tokens, D=64, K=8192. Dominant cost: 16384x8192x64 fp32 GEMM for
// distance argmin (no fp32 MFMA on CDNA4 -> VALU).
// Calibrated model (R15/R16 both ~220us): v_pk_fma_f32 runs fp32 pairs at
// the scalar FLOP rate (4cyc/wave-inst) -> VALU floor 109us theoretical,
// ~167us at m07's measured 103TF. Residual stall: SMEM path (w_t rows
// stride 32KB -> every 64B s_load K$-misses to L2, OOO -> lgkmcnt(0)
// drains), with only 2 MACs per w-float of compute cover.
// R17: 4 tokens/lane -> 32 pk_fma per 64B s_load (2x compute per SMEM byte,
// half the SMEM traffic). Allocator pattern (R8/R9 vs R10/R11): 256-thread
// blocks + 64KB LDS grant up to ~128 VGPRs; 512-thr blocks pin 64. So:
// block = 4 waves sharing a 256-token z_s (64KB); waves split the k-group
// into 4 x 256-code ranges; chunk=16 codes; acc2[4][8]=64 VGPRs, demand ~80.
// grid (64,8) = 512 blocks = 2/CU. Cross-wave combine ascends wid
// (= ascending k) with strict < -> numpy first-min preserved.

#define N_TOK 16384
#define K_EMB 8192
#define EMB_D 64
#define TN 256
#define GROUPS 8
#define KPG (K_EMB / GROUPS)   // 1024 codes per k-group; 256 per wave

typedef float v2f __attribute__((ext_vector_type(2)));

// d_out flat layout (float32), in reference return order:
// z_q (1048576) | loss | new_weight (524288) | new_cluster_size (8192) | new_embed_avg (524288)
#define OFF_LOSS 1048576
#define OFF_W    1048577
#define OFF_CS   1572865
#define OFF_EA   1581057

// scratch inside the z_q region of out (all < 1048576, overwritten by k_quant)
#define OUT_WT 0                        // w_t[d][k]: 64 x 8192 = 524288 floats
#define OUT_CD 524288                   // cand dist [GROUPS][N_TOK] = 131072
#define OUT_CI (524288 + 131072)        // cand idx  [GROUPS][N_TOK] = 131072

// ws float offsets
#define WS_NSUM  0
#define WS_LOSS  1
#define WS_WNORM 16
#define WS_IDX   (WS_WNORM + K_EMB)

// ---------------------------------------------------------------------------
// K0: wnorm[k]; transpose weight -> w_t[d][k] (in out); zero accumulators.
__global__ void k_prep(const float* __restrict__ weight,
                       float* __restrict__ out, float* __restrict__ ws) {
  int gid = blockIdx.x * 256 + threadIdx.x;     // 0..131071
  int row = gid >> 4;                            // codebook row 0..8191
  int l16 = gid & 15;
  float4 w4 = *(const float4*)(weight + row * EMB_D + l16 * 4);
  float s = w4.x * w4.x + w4.y * w4.y + w4.z * w4.z + w4.w * w4.w;
  #pragma unroll
  for (int off = 8; off > 0; off >>= 1) s += __shfl_xor(s, off, 16);
  if (l16 == 0) ws[WS_WNORM + row] = s;

  // transposed copy: w_t[d*8192 + row], d = l16*4+c
  out[OUT_WT + (l16 * 4 + 0) * K_EMB + row] = w4.x;
  out[OUT_WT + (l16 * 4 + 1) * K_EMB + row] = w4.y;
  out[OUT_WT + (l16 * 4 + 2) * K_EMB + row] = w4.z;
  out[OUT_WT + (l16 * 4 + 3) * K_EMB + row] = w4.w;

  #pragma unroll
  for (int j = 0; j < 4; ++j) out[OFF_EA + gid * 4 + j] = 0.f;
  if (gid < K_EMB) out[OFF_CS + gid] = 0.f;
  if (gid == 0) { out[OFF_LOSS] = 0.f; ws[WS_NSUM] = 0.f; ws[WS_LOSS] = 0.f; }
}

// ---------------------------------------------------------------------------
// K1: distance argmin. Block = 256 threads = 4 waves sharing 256 tokens;
// wave w scans k-range [kbase + w*256, +256) in 16 chunks of 16 codes;
// lane owns 4 tokens. grid (64, 8) = 512 blocks = 2/CU.
// Per d-iter: 1 ds_read_b128 (z, 4 tokens) + wave-uniform 64B s_load (w ->
// SGPRs) + 32 v_pk_fma_f32 (acc2[4][8] = 64 VGPRs; the SGPR pair is the one
// scalar operand each pk_fma allows).
__global__ __launch_bounds__(256, 2) void k_argmin(
    const float* __restrict__ z, const float* __restrict__ wt,
    const float* __restrict__ wnorm, float* __restrict__ cd,
    int* __restrict__ ci) {
  __shared__ __align__(16) float z_s[EMB_D * TN];  // [d][n], 64 KB
  const int t = threadIdx.x;
  const int n0 = blockIdx.x * TN;
  const int kbase = blockIdx.y * KPG;
  // z is (b, c, hw): z_flat[n][d] = z[b*65536 + d*1024 + hw], n = b*1024+hw.
  // TN=256 stays within one 1024-aligned b-slab (n0 is a multiple of 256).
  const float* zb = z + ((n0 >> 10) << 16) + (n0 & 1023);

  // 16384 floats = 4096 float4s; 256 threads -> 16 iterations.
  #pragma unroll
  for (int i = 0; i < 16; ++i) {
    int f4 = i * 256 + t;                 // 0..4095 float4s
    int d = f4 >> 6, c4 = (f4 & 63) * 4;
    *(float4*)(z_s + d * TN + c4) = *(const float4*)(zb + d * 1024 + c4);
  }
  __syncthreads();

  const int lane = t & 63;
  // wave id: provably wave-uniform -> w addresses become SGPR (s_load).
  const int wid = __builtin_amdgcn_readfirstlane(t >> 6);  // 0..3
  const int k0base = kbase + wid * 256;
  const float* zlane = z_s + lane * 4;    // this lane's 4 tokens

  float bestd[4];
  int besti[4];
  #pragma unroll
  for (int i = 0; i < 4; ++i) { bestd[i] = 3.4e38f; besti[i] = 0; }

  for (int kc = 0; kc < 16; ++kc) {       // 16 chunks of 16 codes
    const int k0 = k0base + kc * 16;
    const float* wrow = wt + k0;          // + d*K_EMB per d; uniform address

    v2f acc2[4][8];                       // [token][k-pair]
    #pragma unroll
    for (int n = 0; n < 4; ++n)
      #pragma unroll
      for (int p = 0; p < 8; ++p) acc2[n][p] = (v2f)(0.f);

    #pragma unroll 4
    for (int d = 0; d < EMB_D; ++d) {
      float4 zf = *(const float4*)(zlane + d * TN);   // ds_read_b128
      const v2f* wv = (const v2f*)(wrow + (size_t)d * K_EMB);  // s_load 64B
      float zr[4] = {zf.x, zf.y, zf.z, zf.w};
      #pragma unroll
      for (int p = 0; p < 8; ++p) {
        v2f w2 = wv[p];
        #pragma unroll
        for (int n = 0; n < 4; ++n) {
          v2f zn = {zr[n], zr[n]};
          acc2[n][p] = __builtin_elementwise_fma(zn, w2, acc2[n][p]);
        }
      }
    }

    // dist = |w|^2 - 2*dot; k ascends (kc, kk) + strict <  == first-min.
    #pragma unroll
    for (int kk = 0; kk < 16; ++kk) {
      float wn = wnorm[k0 + kk];          // uniform -> scalar load
      #pragma unroll
      for (int n = 0; n < 4; ++n) {
        float dot = (kk & 1) ? acc2[n][kk >> 1].y : acc2[n][kk >> 1].x;
        float dist = fmaf(-2.f, dot, wn);
        if (dist < bestd[n]) { bestd[n] = dist; besti[n] = k0 + kk; }
      }
    }
  }

  // Block combine: stash per-wave bests in z_s (done reading it), then the
  // 256 threads reduce 4 waves in ascending-k order (waves cover ascending
  // k-ranges, so strict < keeps the smaller k on ties).
  __syncthreads();
  #pragma unroll
  for (int i = 0; i < 4; ++i) {
    int n = lane * 4 + i;
    z_s[wid * TN + n] = bestd[i];
    ((int*)z_s)[2048 + wid * TN + n] = besti[i];
  }
  __syncthreads();
  {
    int n = t;
    float bd = z_s[n];
    int bi = ((int*)z_s)[2048 + n];
    #pragma unroll
    for (int w = 1; w < 4; ++w) {
      float od = z_s[w * TN + n];
      int oi = ((int*)z_s)[2048 + w * TN + n];
      if (od < bd) { bd = od; bi = oi; }
    }
    cd[blockIdx.y * N_TOK + n0 + n] = bd;
    ci[blockIdx.y * N_TOK + n0 + n] = bi;
  }
}

// ---------------------------------------------------------------------------
// K2: reduce the GROUPS candidates per token; enc_sum atomics.
// Groups cover ascending k-ranges, so strict < keeps smallest index on tie.
__global__ void k_reduce(const float* __restrict__ cd, const int* __restrict__ ci,
                         int* __restrict__ idx, float* __restrict__ enc) {
  int n = blockIdx.x * 256 + threadIdx.x;
  float bd = cd[n]; int bi = ci[n];
  #pragma unroll
  for (int g = 1; g < GROUPS; ++g) {
    float od = cd[g * N_TOK + n];
    int oi = ci[g * N_TOK + n];
    if (od < bd) { bd = od; bi = oi; }
  }
  idx[n] = bi;
  atomicAdd(enc + bi, 1.0f);
}

// ---------------------------------------------------------------------------
// K3: z_q gather + straight-through output + loss partials + embed_sum atomics.
__global__ void k_quant(const float* __restrict__ z, const float* __restrict__ weight,
                        const int* __restrict__ idx, float* __restrict__ out,
                        float* __restrict__ embed_acc, float* __restrict__ ws) {
  int base = blockIdx.x * 1024 + threadIdx.x;
  float lsum = 0.f;
  #pragma unroll
  for (int i = 0; i < 4; ++i) {
    int e = base + i * 256;               // (b,c,hw) flat, same layout as z
    int c = (e >> 10) & 63;
    int n = ((e >> 16) << 10) | (e & 1023);
    int k = idx[n];
    float zv = z[e];
    float q = weight[k * EMB_D + c];
    out[e] = zv + (q - zv);               // straight-through value
    float d = q - zv;
    lsum += d * d;
    atomicAdd(embed_acc + k * EMB_D + c, zv);
  }
  #pragma unroll
  for (int off = 32; off > 0; off >>= 1) lsum += __shfl_xor(lsum, off, 64);
  __shared__ float red[4];
  int lane = threadIdx.x & 63, wv = threadIdx.x >> 6;
  if (lane == 0) red[wv] = lsum;
  __syncthreads();
  if (threadIdx.x == 0)
    atomicAdd(ws + WS_LOSS, red[0] + red[1] + red[2] + red[3]);
}

// ---------------------------------------------------------------------------
// K4: new_cluster_size (in place over enc_sum), n-sum, loss finalize.
__global__ void k_cluster(const float* __restrict__ cluster_in,
                          float* __restrict__ out, float* __restrict__ ws) {
  int k = blockIdx.x * 256 + threadIdx.x;
  float ncs = cluster_in[k] * 0.99f + 0.01f * out[OFF_CS + k];
  out[OFF_CS + k] = ncs;
  float s = ncs;
  #pragma unroll
  for (int off = 32; off > 0; off >>= 1) s += __shfl_xor(s, off, 64);
  __shared__ float red[4];
  int lane = threadIdx.x & 63, wv = threadIdx.x >> 6;
  if (lane == 0) red[wv] = s;
  __syncthreads();
  if (threadIdx.x == 0) atomicAdd(ws + WS_NSUM, red[0] + red[1] + red[2] + red[3]);
  if (blockIdx.x == 0 && threadIdx.x == 0)
    out[OFF_LOSS] = 0.25f * ws[WS_LOSS] * (1.0f / 1048576.0f);
}

// ---------------------------------------------------------------------------
// K5: smoothed cluster sizes -> new_weight; new_embed_avg (in place).
__global__ void k_final(const float* __restrict__ embed_avg,
                        float* __restrict__ out, const float* __restrict__ ws) {
  int e = blockIdx.x * 256 + threadIdx.x;   // < 524288
  int k = e >> 6;
  float ncs = out[OFF_CS + k];
  float nsum = ws[WS_NSUM];
  float sm = (ncs + 1e-5f) / (nsum + K_EMB * 1e-5f) * nsum;
  float ea = embed_avg[e] * 0.99f + 0.01f * out[OFF_EA + e];
  out[OFF_EA + e] = ea;
  out[OFF_W + e] = ea / sm;
}

// ---------------------------------------------------------------------------
extern "C" void kernel_launch(void* const* d_in, const int* in_sizes, int n_in,
                              void* d_out, int out_size, void* d_ws, size_t ws_size,
                              hipStream_t stream) {
  const float* z = (const float*)d_in[0];
  const float* weight = (const float*)d_in[1];
  const float* cluster = (const float*)d_in[2];
  const float* embed_avg = (const float*)d_in[3];
  float* out = (float*)d_out;
  float* ws = (float*)d_ws;
  float* wnorm = ws + WS_WNORM;
  int* idx = (int*)(ws + WS_IDX);
  float* wt = out + OUT_WT;               // scratch in z_q region
  float* cd = out + OUT_CD;
  int* ci = (int*)(out + OUT_CI);

  hipLaunchKernelGGL(k_prep, dim3(512), dim3(256), 0, stream, weight, out, ws);
  hipLaunchKernelGGL(k_argmin, dim3(N_TOK / TN, GROUPS), dim3(256), 0, stream,
                     z, wt, wnorm, cd, ci);
  hipLaunchKernelGGL(k_reduce, dim3(N_TOK / 256), dim3(256), 0, stream,
                     cd, ci, idx, out + OFF_CS);
  hipLaunchKernelGGL(k_quant, dim3(1024), dim3(256), 0, stream,
                     z, weight, idx, out, out + OFF_EA, ws);
  hipLaunchKernelGGL(k_cluster, dim3(K_EMB / 256), dim3(256), 0, stream,
                     cluster, out, ws);
  hipLaunchKernelGGL(k_final, dim3(524288 / 256), dim3(256), 0, stream,
                     embed_avg, out, ws);
}